// Round 3
// baseline (344.932 us; speedup 1.0000x reference)
//
#include <hip/hip_runtime.h>
#include <math.h>

// Problem constants (fixed by the reference):
// S=2048, B=128, K=64, D=256, T=6, row = T+D = 262 floats.
#define S_DIM 2048
#define B_DIM 128
#define K_DIM 64
#define D_DIM 256
#define T_DIM 6
#define ROW_LEN (T_DIM + D_DIM) /* 262 */
#define LOG_2PI_F 1.8378770664093453f
#define RPB 16 /* rows per block; 16 | 128 so all rows in a block share s. */

typedef float v4f __attribute__((ext_vector_type(4)));

// ---------------------------------------------------------------------------
// R3 = CALIBRATION ROUND, not an optimization.  emb_kernel is launched TWICE
// (idempotent: second launch writes byte-identical values).  dur_us_new -
// dur_us_old = emb's true duration, which two null experiments (occupancy
// 2x in R1, NT->cached in R2) suggest we never actually knew: the "emb=115us"
// attribution assumed the timed window = fill + coef + emb only.
//   dur ~ 335-355  -> emb ~ 50us = at write roofline -> declare ceiling.
//   dur ~ 395-420  -> emb ~ 115us = store path really is capped at ~2.4TB/s
//                     -> persistent-block store-streaming redesign next.
// ---------------------------------------------------------------------------
__global__ __launch_bounds__(256) void coef_kernel(
    const float* __restrict__ means,  // (K,2)
    const float* __restrict__ A,      // (K,2,2)
    const float* __restrict__ W,      // (D,K)
    const float* __restrict__ bvec,   // (D,)
    float* __restrict__ Mt)           // (6,D) in d_ws
{
    __shared__ float c[6][K_DIM];
    int t = threadIdx.x;
    if (t < K_DIM) {
        float a00 = A[4*t+0], a01 = A[4*t+1], a10 = A[4*t+2], a11 = A[4*t+3];
        float cov00 = a00*a00 + a01*a01;            // cov = A A^T (symmetric)
        float cov01 = a00*a10 + a01*a11;
        float cov11 = a10*a10 + a11*a11;
        float det   = cov00*cov11 - cov01*cov01;
        float rdet  = 1.0f / det;
        float i00 =  cov11*rdet, i01 = -cov01*rdet, i11 = cov00*rdet;
        float mx = means[2*t], my = means[2*t+1];
        c[0][t] = -0.5f*(i00*mx*mx + 2.0f*i01*mx*my + i11*my*my + logf(det)) - LOG_2PI_F;
        c[1][t] = i00*mx + i01*my;
        c[2][t] = i01*mx + i11*my;
        c[3][t] = -0.5f*i00;
        c[4][t] = -i01;
        c[5][t] = -0.5f*i11;
    }
    __syncthreads();

    int d = blockIdx.x * 16 + (t >> 4);   // one d per 16 lanes
    int q = t & 15;                       // this lane's k-quad (k = 4q..4q+3)
    float4 w = ((const float4*)W)[blockIdx.x * 256 + t]; // = W[d][4q..4q+3]

    float m[6];
#pragma unroll
    for (int j = 0; j < 6; ++j) {
        const float* cj = &c[j][4*q];
        m[j] = w.x*cj[0] + w.y*cj[1] + w.z*cj[2] + w.w*cj[3];
        // reduce across the 16 lanes of this d-group (lane-aligned groups)
        m[j] += __shfl_xor(m[j], 1);
        m[j] += __shfl_xor(m[j], 2);
        m[j] += __shfl_xor(m[j], 4);
        m[j] += __shfl_xor(m[j], 8);
    }
    if (q == 0) {
        Mt[0*D_DIM + d] = m[0] + bvec[d]; // fold bias into constant term
#pragma unroll
        for (int j = 1; j < 6; ++j)
            Mt[j*D_DIM + d] = m[j];
    }
}

__global__ __launch_bounds__(256, 8) void emb_kernel(
    const float* __restrict__ traj,   // (S,B,T)
    const float* __restrict__ xy,     // (S,B,2)
    const float* __restrict__ pe,     // (MAX_LEN,1,D)
    const float* __restrict__ Mt,     // (6,D)
    float* __restrict__ out)          // (S,B,262)
{
    __shared__ float tile[RPB * ROW_LEN]; // 4192 floats = 16768 B
    __shared__ float xys[2 * RPB];        // x,y per row (32 floats)

    int t    = threadIdx.x;
    int blk  = blockIdx.x;
    int row0 = blk * RPB;
    int s    = row0 >> 7;                 // B = 128; 16 | 128 -> uniform s

    // Cooperative vector loads: 8 float4 of xy, 24 float4 of traj.
    if (t < 8) {                          // xy tile: 32 floats, base blk*128 B
        float4 v = ((const float4*)xy)[blk * 8 + t];
        ((float4*)xys)[t] = v;
    }
    if (t >= 64 && t < 88) {              // traj tile: 96 floats, base blk*384 B
        int i = t - 64;
        float4 v = ((const float4*)traj)[blk * 24 + i];
        int j = i * 4;                    // flat index in 16x6 traj tile
        tile[(j    / T_DIM) * ROW_LEN + (j    % T_DIM)] = v.x;
        tile[((j+1)/ T_DIM) * ROW_LEN + ((j+1)% T_DIM)] = v.y;
        tile[((j+2)/ T_DIM) * ROW_LEN + ((j+2)% T_DIM)] = v.z;
        tile[((j+3)/ T_DIM) * ROW_LEN + ((j+3)% T_DIM)] = v.w;
    }

    // Per-thread rank-6 coefficients (d = t), pe folded into the constant term.
    float m0 = Mt[0*D_DIM + t] + pe[s*D_DIM + t];
    float m1 = Mt[1*D_DIM + t], m2 = Mt[2*D_DIM + t];
    float m3 = Mt[3*D_DIM + t], m4 = Mt[4*D_DIM + t], m5 = Mt[5*D_DIM + t];

    __syncthreads();

    // Phase 1: evaluate emb for 16 rows into LDS (lane-consecutive: conflict-
    // free).  Read xys two rows at a time (float4 broadcast: x0,y0,x1,y1).
#pragma unroll
    for (int r2 = 0; r2 < RPB / 2; ++r2) {
        float4 p = ((const float4*)xys)[r2];
        float v0 = m0 + m1*p.x + m2*p.y + (m3*p.x + m4*p.y)*p.x + m5*p.y*p.y;
        float v1 = m0 + m1*p.z + m2*p.w + (m3*p.z + m4*p.w)*p.z + m5*p.w*p.w;
        tile[(2*r2    ) * ROW_LEN + T_DIM + t] = v0;
        tile[(2*r2 + 1) * ROW_LEN + T_DIM + t] = v1;
    }

    __syncthreads();

    // Phase 2: aligned float4 copy LDS -> global (cache-routed).
    // 16*262 = 4192 floats = 1048 float4 = 4*256 + 24.
    const v4f* t4 = (const v4f*)tile;
    v4f* o4 = (v4f*)(out + (size_t)row0 * ROW_LEN); // base blk*16768 B, 64B-aligned
#pragma unroll
    for (int k = 0; k < 4; ++k)
        o4[k * 256 + t] = t4[k * 256 + t];
    if (t < 24)
        o4[1024 + t] = t4[1024 + t];
}

extern "C" void kernel_launch(void* const* d_in, const int* in_sizes, int n_in,
                              void* d_out, int out_size, void* d_ws, size_t ws_size,
                              hipStream_t stream) {
    const float* traj  = (const float*)d_in[0]; // (S,B,T)
    const float* xy    = (const float*)d_in[1]; // (S,B,2)
    const float* means = (const float*)d_in[2]; // (K,2)
    const float* A     = (const float*)d_in[3]; // (K,2,2)
    const float* W     = (const float*)d_in[4]; // (D,K)
    const float* bvec  = (const float*)d_in[5]; // (D,)
    const float* pe    = (const float*)d_in[6]; // (MAX_LEN,1,D)
    float* out = (float*)d_out;
    float* Mt  = (float*)d_ws; // 6*D*4 = 6 KB

    coef_kernel<<<16, 256, 0, stream>>>(means, A, W, bvec, Mt);

    int nrows = S_DIM * B_DIM;           // 262144
    int grid  = nrows / RPB;             // 16384 blocks

    // CALIBRATION: run emb twice (idempotent).  dur_us delta vs R2 = emb's
    // true per-launch duration.  See header comment for the decision rule.
    emb_kernel<<<grid, 256, 0, stream>>>(traj, xy, pe, Mt, out);
    emb_kernel<<<grid, 256, 0, stream>>>(traj, xy, pe, Mt, out);
}

// Round 4
// 293.195 us; speedup vs baseline: 1.1765x; 1.1765x over previous
//
#include <hip/hip_runtime.h>
#include <math.h>

// Problem constants (fixed by the reference):
// S=2048, B=128, K=64, D=256, T=6, row = T+D = 262 floats.
#define S_DIM 2048
#define B_DIM 128
#define K_DIM 64
#define D_DIM 256
#define T_DIM 6
#define ROW_LEN (T_DIM + D_DIM) /* 262 */
#define LOG_2PI_F 1.8378770664093453f
#define RPB 16 /* rows per block; 16 | 128 so all rows in a block share s.
                  LDS = 16.9 KB -> 8 blocks/CU = 32 waves/CU. */

typedef float v4f __attribute__((ext_vector_type(4)));

// ---------------------------------------------------------------------------
// R4 = revert of the R3 calibration (double emb launch removed).
//
// Session findings (R0-R3):
//  - emb_kernel true duration = 51.4 us (measured by idempotent double-launch
//    delta in R3), moving 283 MB -> 5.5 TB/s = 88% of the 6.3 TB/s achievable
//    ceiling.  Write-roofline floor for the mandatory 274.7 MB output is
//    ~45 us.  Remaining gap ~6 us = within bench noise.
//  - The other ~240 us of the timed window is harness-fixed: 175 us output
//    re-poison fill (fillBufferAligned, itself running at 6.1-6.3 TB/s),
//    reset memsets, launch overhead, ~3 us coef_kernel.
//  - Occupancy 4->8 blocks/CU (R1) and NT->cached stores (R2) were both
//    exact nulls, as expected for a kernel already at the memory wall.
// ---------------------------------------------------------------------------
__global__ __launch_bounds__(256) void coef_kernel(
    const float* __restrict__ means,  // (K,2)
    const float* __restrict__ A,      // (K,2,2)
    const float* __restrict__ W,      // (D,K)
    const float* __restrict__ bvec,   // (D,)
    float* __restrict__ Mt)           // (6,D) in d_ws
{
    __shared__ float c[6][K_DIM];
    int t = threadIdx.x;
    if (t < K_DIM) {
        float a00 = A[4*t+0], a01 = A[4*t+1], a10 = A[4*t+2], a11 = A[4*t+3];
        float cov00 = a00*a00 + a01*a01;            // cov = A A^T (symmetric)
        float cov01 = a00*a10 + a01*a11;
        float cov11 = a10*a10 + a11*a11;
        float det   = cov00*cov11 - cov01*cov01;
        float rdet  = 1.0f / det;
        float i00 =  cov11*rdet, i01 = -cov01*rdet, i11 = cov00*rdet;
        float mx = means[2*t], my = means[2*t+1];
        c[0][t] = -0.5f*(i00*mx*mx + 2.0f*i01*mx*my + i11*my*my + logf(det)) - LOG_2PI_F;
        c[1][t] = i00*mx + i01*my;
        c[2][t] = i01*mx + i11*my;
        c[3][t] = -0.5f*i00;
        c[4][t] = -i01;
        c[5][t] = -0.5f*i11;
    }
    __syncthreads();

    int d = blockIdx.x * 16 + (t >> 4);   // one d per 16 lanes
    int q = t & 15;                       // this lane's k-quad (k = 4q..4q+3)
    float4 w = ((const float4*)W)[blockIdx.x * 256 + t]; // = W[d][4q..4q+3]

    float m[6];
#pragma unroll
    for (int j = 0; j < 6; ++j) {
        const float* cj = &c[j][4*q];
        m[j] = w.x*cj[0] + w.y*cj[1] + w.z*cj[2] + w.w*cj[3];
        // reduce across the 16 lanes of this d-group (lane-aligned groups)
        m[j] += __shfl_xor(m[j], 1);
        m[j] += __shfl_xor(m[j], 2);
        m[j] += __shfl_xor(m[j], 4);
        m[j] += __shfl_xor(m[j], 8);
    }
    if (q == 0) {
        Mt[0*D_DIM + d] = m[0] + bvec[d]; // fold bias into constant term
#pragma unroll
        for (int j = 1; j < 6; ++j)
            Mt[j*D_DIM + d] = m[j];
    }
}

__global__ __launch_bounds__(256, 8) void emb_kernel(
    const float* __restrict__ traj,   // (S,B,T)
    const float* __restrict__ xy,     // (S,B,2)
    const float* __restrict__ pe,     // (MAX_LEN,1,D)
    const float* __restrict__ Mt,     // (6,D)
    float* __restrict__ out)          // (S,B,262)
{
    __shared__ float tile[RPB * ROW_LEN]; // 4192 floats = 16768 B
    __shared__ float xys[2 * RPB];        // x,y per row (32 floats)

    int t    = threadIdx.x;
    int blk  = blockIdx.x;
    int row0 = blk * RPB;
    int s    = row0 >> 7;                 // B = 128; 16 | 128 -> uniform s

    // Cooperative vector loads: 8 float4 of xy, 24 float4 of traj.
    if (t < 8) {                          // xy tile: 32 floats, base blk*128 B
        float4 v = ((const float4*)xy)[blk * 8 + t];
        ((float4*)xys)[t] = v;
    }
    if (t >= 64 && t < 88) {              // traj tile: 96 floats, base blk*384 B
        int i = t - 64;
        float4 v = ((const float4*)traj)[blk * 24 + i];
        int j = i * 4;                    // flat index in 16x6 traj tile
        tile[(j    / T_DIM) * ROW_LEN + (j    % T_DIM)] = v.x;
        tile[((j+1)/ T_DIM) * ROW_LEN + ((j+1)% T_DIM)] = v.y;
        tile[((j+2)/ T_DIM) * ROW_LEN + ((j+2)% T_DIM)] = v.z;
        tile[((j+3)/ T_DIM) * ROW_LEN + ((j+3)% T_DIM)] = v.w;
    }

    // Per-thread rank-6 coefficients (d = t), pe folded into the constant term.
    float m0 = Mt[0*D_DIM + t] + pe[s*D_DIM + t];
    float m1 = Mt[1*D_DIM + t], m2 = Mt[2*D_DIM + t];
    float m3 = Mt[3*D_DIM + t], m4 = Mt[4*D_DIM + t], m5 = Mt[5*D_DIM + t];

    __syncthreads();

    // Phase 1: evaluate emb for 16 rows into LDS (lane-consecutive: conflict-
    // free).  Read xys two rows at a time (float4 broadcast: x0,y0,x1,y1).
#pragma unroll
    for (int r2 = 0; r2 < RPB / 2; ++r2) {
        float4 p = ((const float4*)xys)[r2];
        float v0 = m0 + m1*p.x + m2*p.y + (m3*p.x + m4*p.y)*p.x + m5*p.y*p.y;
        float v1 = m0 + m1*p.z + m2*p.w + (m3*p.z + m4*p.w)*p.z + m5*p.w*p.w;
        tile[(2*r2    ) * ROW_LEN + T_DIM + t] = v0;
        tile[(2*r2 + 1) * ROW_LEN + T_DIM + t] = v1;
    }

    __syncthreads();

    // Phase 2: aligned nontemporal float4 copy LDS -> global.
    // 16*262 = 4192 floats = 1048 float4 = 4*256 + 24.
    const v4f* t4 = (const v4f*)tile;
    v4f* o4 = (v4f*)(out + (size_t)row0 * ROW_LEN); // base blk*16768 B, 64B-aligned
#pragma unroll
    for (int k = 0; k < 4; ++k)
        __builtin_nontemporal_store(t4[k * 256 + t], &o4[k * 256 + t]);
    if (t < 24)
        __builtin_nontemporal_store(t4[1024 + t], &o4[1024 + t]);
}

extern "C" void kernel_launch(void* const* d_in, const int* in_sizes, int n_in,
                              void* d_out, int out_size, void* d_ws, size_t ws_size,
                              hipStream_t stream) {
    const float* traj  = (const float*)d_in[0]; // (S,B,T)
    const float* xy    = (const float*)d_in[1]; // (S,B,2)
    const float* means = (const float*)d_in[2]; // (K,2)
    const float* A     = (const float*)d_in[3]; // (K,2,2)
    const float* W     = (const float*)d_in[4]; // (D,K)
    const float* bvec  = (const float*)d_in[5]; // (D,)
    const float* pe    = (const float*)d_in[6]; // (MAX_LEN,1,D)
    float* out = (float*)d_out;
    float* Mt  = (float*)d_ws; // 6*D*4 = 6 KB

    coef_kernel<<<16, 256, 0, stream>>>(means, A, W, bvec, Mt);

    int nrows = S_DIM * B_DIM;           // 262144
    int grid  = nrows / RPB;             // 16384 blocks
    emb_kernel<<<grid, 256, 0, stream>>>(traj, xy, pe, Mt, out);
}